// Round 3
// baseline (2171.638 us; speedup 1.0000x reference)
//
#include <hip/hip_runtime.h>
#include <hip/hip_bf16.h>

// RelationAwareSelfAttention  N=500, DM=DK=DV=2048, KWIN=10
// Inputs (f32; bf16 auto-detected as insurance): X[500,2048], mask[500,500] i32,
//   Wq/Wk/Wv/Wo[2048,2048], wk[21,2048]
// Outputs (f32, concat): Y[500,2048], A[500,500]

#define N_TOK 500
#define DMODEL 2048
#define KWIN_ 10
#define NREL 21

typedef __hip_bfloat16 bf16;

__device__ inline float loadf(const void* p, long i, int bf) {
  if (bf) return __bfloat162float(((const bf16*)p)[i]);
  return ((const float*)p)[i];
}

// Detect input dtype from X: low 16 bits of first 256 32-bit slots.
// bf16 N(0,1) never has exponent >= 140 there; f32 low-halves are random bits.
__global__ void detect_kernel(const unsigned short* X, int* flagp) {
  __shared__ int cnt;
  if (threadIdx.x == 0) cnt = 0;
  __syncthreads();
  unsigned short u = X[(long)threadIdx.x * 2];
  int e = (u >> 7) & 0xFF;
  if (e >= 140) atomicAdd(&cnt, 1);
  __syncthreads();
  if (threadIdx.x == 0) *flagp = (cnt >= 8) ? 0 : 1;  // 1 => bf16 inputs
}

// Guarded GEMM: C[M,N] = alpha * A[M,K] @ B ([K,N] if !TRANSB, [N,K] if TRANSB)
// 64x64 tile, BK=16, 256 threads, 4x4 micro-tile, f32 accumulate. C is f32.
template <bool TRANSB>
__global__ __launch_bounds__(256) void gemm_kernel(
    const void* __restrict__ A, const void* __restrict__ B,
    float* __restrict__ C, int M, int N, int K, int lda, int ldb, int ldc,
    float alpha, const int* __restrict__ flagp, int modeA, int modeB) {
  const int BM = 64, BN = 64, BK = 16;
  __shared__ float As[BK][BM + 1];
  __shared__ float Bs[BK][BN + 1];
  int bfA = (modeA == 2) ? *flagp : modeA;
  int bfB = (modeB == 2) ? *flagp : modeB;
  int tid = threadIdx.x;
  int tx = tid & 15, ty = tid >> 4;
  int row0 = blockIdx.y * BM, col0 = blockIdx.x * BN;
  float acc[4][4] = {};
  for (int k0 = 0; k0 < K; k0 += BK) {
    for (int l = tid; l < BM * BK; l += 256) {
      int m = l >> 4, kk = l & 15;
      int r = row0 + m, k = k0 + kk;
      As[kk][m] = (r < M && k < K) ? loadf(A, (long)r * lda + k, bfA) : 0.f;
    }
    if (!TRANSB) {
      for (int l = tid; l < BK * BN; l += 256) {
        int kk = l >> 6, n = l & 63;
        int k = k0 + kk, c = col0 + n;
        Bs[kk][n] = (k < K && c < N) ? loadf(B, (long)k * ldb + c, bfB) : 0.f;
      }
    } else {
      for (int l = tid; l < BK * BN; l += 256) {
        int n = l >> 4, kk = l & 15;
        int k = k0 + kk, c = col0 + n;
        Bs[kk][n] = (k < K && c < N) ? loadf(B, (long)c * ldb + k, bfB) : 0.f;
      }
    }
    __syncthreads();
#pragma unroll
    for (int kk = 0; kk < BK; ++kk) {
      float a[4], b[4];
#pragma unroll
      for (int m = 0; m < 4; ++m) a[m] = As[kk][ty * 4 + m];
#pragma unroll
      for (int n = 0; n < 4; ++n) b[n] = Bs[kk][tx * 4 + n];
#pragma unroll
      for (int m = 0; m < 4; ++m)
#pragma unroll
        for (int n = 0; n < 4; ++n) acc[m][n] += a[m] * b[n];
    }
    __syncthreads();
  }
#pragma unroll
  for (int m = 0; m < 4; ++m) {
    int r = row0 + ty * 4 + m;
    if (r >= M) continue;
#pragma unroll
    for (int n = 0; n < 4; ++n) {
      int c = col0 + tx * 4 + n;
      if (c < N) C[(long)r * ldc + c] = alpha * acc[m][n];
    }
  }
}

// QR[i,r] = sum_d Qs[i,d] * wk[r,d]; Qs is f32 ws, wk is poly-dtype.
__global__ __launch_bounds__(256) void qr_kernel(const float* __restrict__ Q,
                                                 const void* __restrict__ wk,
                                                 float* __restrict__ QR,
                                                 const int* __restrict__ flagp) {
  int i = blockIdx.x;
  int bf = *flagp;
  int lane = threadIdx.x & 63, wid = threadIdx.x >> 6;
  for (int r = wid; r < NREL; r += 4) {
    float p = 0.f;
    for (int d = lane; d < DMODEL; d += 64)
      p += Q[(long)i * DMODEL + d] * loadf(wk, (long)r * DMODEL + d, bf);
#pragma unroll
    for (int o = 32; o > 0; o >>= 1) p += __shfl_down(p, o);
    if (lane == 0) QR[i * NREL + r] = p;
  }
}

// Per-row: bias + mask + softmax -> Aout (f32, lives in d_out).
__global__ __launch_bounds__(256) void softmax_kernel(
    const float* __restrict__ S, const float* __restrict__ QR,
    const int* __restrict__ mask, float* __restrict__ Aout) {
  int i = blockIdx.x;
  int tid = threadIdx.x;
  int lane = tid & 63, wid = tid >> 6;
  __shared__ float red[4];

  float v0 = -1e30f, v1 = -1e30f;
  int j0 = tid, j1 = tid + 256;
  if (j0 < N_TOK) {
    int rel = j0 - i;
    rel = rel < -KWIN_ ? -KWIN_ : (rel > KWIN_ ? KWIN_ : rel);
    float s = S[(long)i * N_TOK + j0] + QR[i * NREL + rel + KWIN_];
    if (mask[(long)i * N_TOK + j0] == 0) s = -1e9f;
    v0 = s;
  }
  if (j1 < N_TOK) {
    int rel = j1 - i;
    rel = rel < -KWIN_ ? -KWIN_ : (rel > KWIN_ ? KWIN_ : rel);
    float s = S[(long)i * N_TOK + j1] + QR[i * NREL + rel + KWIN_];
    if (mask[(long)i * N_TOK + j1] == 0) s = -1e9f;
    v1 = s;
  }
  float mx = fmaxf(v0, v1);
#pragma unroll
  for (int o = 32; o > 0; o >>= 1) mx = fmaxf(mx, __shfl_down(mx, o));
  if (lane == 0) red[wid] = mx;
  __syncthreads();
  if (tid == 0) red[0] = fmaxf(fmaxf(red[0], red[1]), fmaxf(red[2], red[3]));
  __syncthreads();
  mx = red[0];
  __syncthreads();
  float e0 = (j0 < N_TOK) ? expf(v0 - mx) : 0.f;
  float e1 = (j1 < N_TOK) ? expf(v1 - mx) : 0.f;
  float sum = e0 + e1;
#pragma unroll
  for (int o = 32; o > 0; o >>= 1) sum += __shfl_down(sum, o);
  if (lane == 0) red[wid] = sum;
  __syncthreads();
  if (tid == 0) red[0] = red[0] + red[1] + red[2] + red[3];
  __syncthreads();
  float inv = 1.f / red[0];
  if (j0 < N_TOK) Aout[(long)i * N_TOK + j0] = e0 * inv;
  if (j1 < N_TOK) Aout[(long)i * N_TOK + j1] = e1 * inv;
}

extern "C" void kernel_launch(void* const* d_in, const int* in_sizes, int n_in,
                              void* d_out, int out_size, void* d_ws,
                              size_t ws_size, hipStream_t stream) {
  const void* X = d_in[0];
  const int* mask = (const int*)d_in[1];
  const void* Wq = d_in[2];
  const void* Wk = d_in[3];
  const void* Wv = d_in[4];
  const void* Wo = d_in[5];
  const void* wk = d_in[6];

  float* Yout = (float*)d_out;                // [500,2048] f32
  float* Aout = Yout + (long)N_TOK * DMODEL;  // [500,500]  f32

  // ws layout: [flag int][pad] Q K V AV (f32) S QR
  int* flag = (int*)d_ws;
  float* base = (float*)d_ws + 16;
  float* Q = base;                        // 500*2048 (holds Qs = scale*Q)
  float* Kp = Q + (long)N_TOK * DMODEL;   // 500*2048
  float* V = Kp + (long)N_TOK * DMODEL;   // 500*2048
  float* AV = V + (long)N_TOK * DMODEL;   // 500*2048
  float* S = AV + (long)N_TOK * DMODEL;   // 500*500
  float* QR = S + (long)N_TOK * N_TOK;    // 500*21

  const float scale = 0.022097086912079608f;  // 1/sqrt(2048)

  dim3 blk(256);
  dim3 g_big(DMODEL / 64, (N_TOK + 63) / 64);      // (32, 8)
  dim3 g_s((N_TOK + 63) / 64, (N_TOK + 63) / 64);  // (8, 8)

  detect_kernel<<<1, 256, 0, stream>>>((const unsigned short*)X, flag);

  // Qs = scale * X @ Wq ; K = X @ Wk ; V = X @ Wv
  gemm_kernel<false><<<g_big, blk, 0, stream>>>(
      X, Wq, Q, N_TOK, DMODEL, DMODEL, DMODEL, DMODEL, DMODEL, scale, flag, 2, 2);
  gemm_kernel<false><<<g_big, blk, 0, stream>>>(
      X, Wk, Kp, N_TOK, DMODEL, DMODEL, DMODEL, DMODEL, DMODEL, 1.f, flag, 2, 2);
  gemm_kernel<false><<<g_big, blk, 0, stream>>>(
      X, Wv, V, N_TOK, DMODEL, DMODEL, DMODEL, DMODEL, DMODEL, 1.f, flag, 2, 2);

  // QR = Qs @ wk^T  [500,21]
  qr_kernel<<<dim3(N_TOK), blk, 0, stream>>>(Q, wk, QR, flag);

  // S = Qs @ K^T  [500,500]
  gemm_kernel<true><<<g_s, blk, 0, stream>>>(
      Q, Kp, S, N_TOK, N_TOK, DMODEL, DMODEL, DMODEL, N_TOK, 1.f, flag, 0, 0);

  // bias + mask + softmax -> Aout (f32, in d_out)
  softmax_kernel<<<dim3(N_TOK), blk, 0, stream>>>(S, QR, mask, Aout);

  // AV = A @ V  [500,2048]  (A read from d_out)
  gemm_kernel<false><<<g_big, blk, 0, stream>>>(
      Aout, V, AV, N_TOK, DMODEL, N_TOK, N_TOK, DMODEL, DMODEL, 1.f, flag, 0, 0);

  // Y = AV @ Wo -> f32 out
  gemm_kernel<false><<<g_big, blk, 0, stream>>>(
      AV, Wo, Yout, N_TOK, DMODEL, DMODEL, DMODEL, DMODEL, DMODEL, 1.f, flag, 0, 2);
}

// Round 4
// 293.249 us; speedup vs baseline: 7.4054x; 7.4054x over previous
//
#include <hip/hip_runtime.h>
#include <hip/hip_bf16.h>

// RelationAwareSelfAttention  N=500, DM=DK=DV=2048, KWIN=10
// Inputs f32: X[500,2048], mask[500,500] i32, Wq/Wk/Wv/Wo[2048,2048], wk[21,2048]
// Outputs f32 concat: Y[500,2048], A[500,500]
// Round 4: all matmuls on bf16 MFMA 16x16x32, NT form, M padded to 512.

#define N_TOK 500
#define MP 512
#define DM 2048
#define KWIN_ 10
#define NREL 21

typedef __hip_bfloat16 bf16;
typedef __attribute__((ext_vector_type(8))) short short8;
typedef __attribute__((ext_vector_type(4))) float floatx4;

__device__ inline void store_c(float* p, float v) { *p = v; }
__device__ inline void store_c(bf16* p, float v) { *p = __float2bfloat16(v); }

// f32 -> bf16 copy with zero row padding. cols fixed 2048, 256 thr x 8 elems.
__global__ __launch_bounds__(256) void cvt_rows(const float* __restrict__ in,
                                                bf16* __restrict__ out,
                                                int rows) {
  int r = blockIdx.x;
  int c0 = threadIdx.x * 8;
  bf16 v[8];
  if (r < rows) {
    const float* p = in + (long)r * DM + c0;
#pragma unroll
    for (int j = 0; j < 8; ++j) v[j] = __float2bfloat16(p[j]);
  } else {
#pragma unroll
    for (int j = 0; j < 8; ++j) v[j] = __float2bfloat16(0.f);
  }
  *(short8*)(out + (long)r * DM + c0) = *(short8*)v;
}

// W[2048,2048] f32 -> Wt[n][k] = bf16(W[k][n]). 64x64 LDS tile transpose.
__global__ __launch_bounds__(256) void transpose_w(const float* __restrict__ W,
                                                   bf16* __restrict__ Wt) {
  __shared__ float t[64][65];
  int k0 = blockIdx.y * 64, n0 = blockIdx.x * 64;
  int c = threadIdx.x & 63, r4 = threadIdx.x >> 6;
#pragma unroll
  for (int i = 0; i < 16; ++i) {
    int r = r4 * 16 + i;
    t[r][c] = W[(long)(k0 + r) * DM + n0 + c];
  }
  __syncthreads();
#pragma unroll
  for (int i = 0; i < 16; ++i) {
    int r = r4 * 16 + i;
    Wt[(long)(n0 + r) * DM + k0 + c] = __float2bfloat16(t[c][r]);
  }
}

// NT MFMA GEMM: C[M,N] = alpha * A[M,K] @ B[N,K]^T  (bf16 in, f32 acc)
// 64x64 tile, BK=32, 256 thr (4 waves), each wave 32x32 via 2x2 mfma 16x16x32.
// Grid: (N/64, M/64). Rows >= m_store not stored.
template <typename CT>
__global__ __launch_bounds__(256) void gemm_nt(
    const bf16* __restrict__ A, int lda, const bf16* __restrict__ B, int ldb,
    CT* __restrict__ C, int ldc, int K, float alpha, int m_store) {
  __shared__ __align__(16) bf16 As[64][40];  // +8 pad
  __shared__ __align__(16) bf16 Bs[64][40];
  int tid = threadIdx.x;
  int row0 = blockIdx.y * 64, col0 = blockIdx.x * 64;
  int sr = tid >> 2, sk = (tid & 3) * 8;     // staging: row, k-offset (8 bf16)
  int lane = tid & 63, w = tid >> 6;
  int wr = (w & 1) * 32, wc = (w >> 1) * 32; // wave 32x32 sub-tile
  int l16 = lane & 15, l4 = lane >> 4;
  floatx4 acc[2][2] = {};
  const bf16* ap = A + (long)(row0 + sr) * lda + sk;
  const bf16* bp = B + (long)(col0 + sr) * ldb + sk;
  for (int k0 = 0; k0 < K; k0 += 32) {
    *(short8*)&As[sr][sk] = *(const short8*)(ap + k0);
    *(short8*)&Bs[sr][sk] = *(const short8*)(bp + k0);
    __syncthreads();
    short8 af0 = *(short8*)&As[wr + l16][l4 * 8];
    short8 af1 = *(short8*)&As[wr + 16 + l16][l4 * 8];
    short8 bg0 = *(short8*)&Bs[wc + l16][l4 * 8];
    short8 bg1 = *(short8*)&Bs[wc + 16 + l16][l4 * 8];
    acc[0][0] = __builtin_amdgcn_mfma_f32_16x16x32_bf16(af0, bg0, acc[0][0], 0, 0, 0);
    acc[0][1] = __builtin_amdgcn_mfma_f32_16x16x32_bf16(af0, bg1, acc[0][1], 0, 0, 0);
    acc[1][0] = __builtin_amdgcn_mfma_f32_16x16x32_bf16(af1, bg0, acc[1][0], 0, 0, 0);
    acc[1][1] = __builtin_amdgcn_mfma_f32_16x16x32_bf16(af1, bg1, acc[1][1], 0, 0, 0);
    __syncthreads();
  }
  // C layout: col = lane&15, row = (lane>>4)*4 + i  [m89-verified]
#pragma unroll
  for (int mi = 0; mi < 2; ++mi)
#pragma unroll
    for (int ni = 0; ni < 2; ++ni)
#pragma unroll
      for (int i = 0; i < 4; ++i) {
        int r = row0 + wr + mi * 16 + l4 * 4 + i;
        if (r >= m_store) continue;
        int c = col0 + wc + ni * 16 + l16;
        store_c(&C[(long)r * ldc + c], alpha * acc[mi][ni][i]);
      }
}

// QR[i,r] = sum_d Qs[i,d] * wkb[r,d]  (Qs already scaled). QR ld = 32.
__global__ __launch_bounds__(256) void qr_kernel(const bf16* __restrict__ Q,
                                                 const bf16* __restrict__ wkb,
                                                 float* __restrict__ QR) {
  int i = blockIdx.x;
  int lane = threadIdx.x & 63, wid = threadIdx.x >> 6;
  for (int r = wid; r < NREL; r += 4) {
    float p = 0.f;
    for (int d = lane * 8; d < DM; d += 64 * 8) {
      short8 q8 = *(const short8*)(Q + (long)i * DM + d);
      short8 w8 = *(const short8*)(wkb + (long)r * DM + d);
#pragma unroll
      for (int j = 0; j < 8; ++j)
        p += __bfloat162float(((const bf16*)&q8)[j]) *
             __bfloat162float(((const bf16*)&w8)[j]);
    }
#pragma unroll
    for (int o = 32; o > 0; o >>= 1) p += __shfl_down(p, o);
    if (lane == 0) QR[i * 32 + r] = p;
  }
}

// bias + mask + softmax. S ld=MP. Writes Aout f32 (d_out, 500x500) and
// Abf bf16 [512][512] zero-padded (rows>=500 and cols>=500 are 0).
__global__ __launch_bounds__(256) void softmax_kernel(
    const float* __restrict__ S, const float* __restrict__ QR,
    const int* __restrict__ mask, float* __restrict__ Aout,
    bf16* __restrict__ Abf) {
  int i = blockIdx.x;
  int tid = threadIdx.x;
  if (i >= N_TOK) {  // pad rows: zero Abf
    Abf[(long)i * MP + tid] = __float2bfloat16(0.f);
    Abf[(long)i * MP + tid + 256] = __float2bfloat16(0.f);
    return;
  }
  int lane = tid & 63, wid = tid >> 6;
  __shared__ float red[4];
  float v0 = -1e30f, v1 = -1e30f;
  int j0 = tid, j1 = tid + 256;
  {
    int rel = j0 - i;
    rel = rel < -KWIN_ ? -KWIN_ : (rel > KWIN_ ? KWIN_ : rel);
    float s = S[(long)i * MP + j0] + QR[i * 32 + rel + KWIN_];
    if (mask[(long)i * N_TOK + j0] == 0) s = -1e9f;
    v0 = s;  // j0 < 500 always (tid < 256)
  }
  if (j1 < N_TOK) {
    int rel = j1 - i;
    rel = rel < -KWIN_ ? -KWIN_ : (rel > KWIN_ ? KWIN_ : rel);
    float s = S[(long)i * MP + j1] + QR[i * 32 + rel + KWIN_];
    if (mask[(long)i * N_TOK + j1] == 0) s = -1e9f;
    v1 = s;
  }
  float mx = fmaxf(v0, v1);
#pragma unroll
  for (int o = 32; o > 0; o >>= 1) mx = fmaxf(mx, __shfl_down(mx, o));
  if (lane == 0) red[wid] = mx;
  __syncthreads();
  if (tid == 0) red[0] = fmaxf(fmaxf(red[0], red[1]), fmaxf(red[2], red[3]));
  __syncthreads();
  mx = red[0];
  __syncthreads();
  float e0 = expf(v0 - mx);
  float e1 = (j1 < N_TOK) ? expf(v1 - mx) : 0.f;
  float sum = e0 + e1;
#pragma unroll
  for (int o = 32; o > 0; o >>= 1) sum += __shfl_down(sum, o);
  if (lane == 0) red[wid] = sum;
  __syncthreads();
  if (tid == 0) red[0] = red[0] + red[1] + red[2] + red[3];
  __syncthreads();
  float inv = 1.f / red[0];
  float a0 = e0 * inv, a1 = e1 * inv;
  Aout[(long)i * N_TOK + j0] = a0;
  if (j1 < N_TOK) Aout[(long)i * N_TOK + j1] = a1;
  Abf[(long)i * MP + j0] = __float2bfloat16(a0);
  Abf[(long)i * MP + j1] = __float2bfloat16(a1);  // j1>=500 -> a1==0
}

extern "C" void kernel_launch(void* const* d_in, const int* in_sizes, int n_in,
                              void* d_out, int out_size, void* d_ws,
                              size_t ws_size, hipStream_t stream) {
  const float* X = (const float*)d_in[0];
  const int* mask = (const int*)d_in[1];
  const float* Wq = (const float*)d_in[2];
  const float* Wk = (const float*)d_in[3];
  const float* Wv = (const float*)d_in[4];
  const float* Wo = (const float*)d_in[5];
  const float* wk = (const float*)d_in[6];

  float* Yout = (float*)d_out;                // [500,2048]
  float* Aout = Yout + (long)N_TOK * DM;      // [500,500]

  // ws layout (bytes), total ~17.2 MB (Round 3 used 18.4 MB OK):
  char* p = (char*)d_ws;
  bf16* Xb = (bf16*)p;                        // [512][2048]  2 MB
  bf16* Wt = (bf16*)(p + 2097152);            // [2048][2048] 8 MB (reused 4x)
  bf16* Qs = (bf16*)(p + 10485760);           // [512][2048]  2 MB (later AVb)
  bf16* Kb = (bf16*)(p + 12582912);           // [512][2048]  2 MB (later Abf)
  bf16* Vt = (bf16*)(p + 14680064);           // [2048][512]  2 MB
  float* S = (float*)(p + 16777216);          // [512][512]   1 MB
  bf16* wkb = (bf16*)(p + 17825792);          // [21][2048]
  float* QR = (float*)(p + 17956864);         // [512][32]
  bf16* AVb = Qs;                             // reuse after S GEMM + qr
  bf16* Abf = Kb;                             // reuse after S GEMM

  const float scale = 0.022097086912079608f;  // 1/sqrt(2048)

  dim3 blk(256);
  dim3 g_tr(32, 32);
  dim3 g_qkv(32, 8);   // N=2048, M=512
  dim3 g_vt(8, 32);    // N=512,  M=2048
  dim3 g_s(8, 8);      // N=512,  M=512

  cvt_rows<<<MP, blk, 0, stream>>>(X, Xb, N_TOK);
  cvt_rows<<<NREL, blk, 0, stream>>>(wk, wkb, NREL);

  // Qs = scale * X @ Wq   (Wt = Wq^T)
  transpose_w<<<g_tr, blk, 0, stream>>>(Wq, Wt);
  gemm_nt<bf16><<<g_qkv, blk, 0, stream>>>(Xb, DM, Wt, DM, Qs, DM, DM, scale, MP);
  // Kb = X @ Wk
  transpose_w<<<g_tr, blk, 0, stream>>>(Wk, Wt);
  gemm_nt<bf16><<<g_qkv, blk, 0, stream>>>(Xb, DM, Wt, DM, Kb, DM, DM, 1.f, MP);
  // Vt = (X @ Wv)^T = NT(Wv^T, X):  [2048,512]
  transpose_w<<<g_tr, blk, 0, stream>>>(Wv, Wt);
  gemm_nt<bf16><<<g_vt, blk, 0, stream>>>(Wt, DM, Xb, DM, Vt, MP, DM, 1.f, DM);

  // QR = Qs @ wk^T
  qr_kernel<<<N_TOK, blk, 0, stream>>>(Qs, wkb, QR);

  // S = Qs @ K^T  [512,512] f32
  gemm_nt<float><<<g_s, blk, 0, stream>>>(Qs, DM, Kb, DM, S, MP, DM, 1.f, MP);

  // softmax -> Aout (d_out) + Abf (bf16, padded)
  softmax_kernel<<<MP, blk, 0, stream>>>(S, QR, mask, Aout, Abf);

  // AV = A @ V = NT(Abf, Vt)  [512,2048] bf16
  gemm_nt<bf16><<<g_qkv, blk, 0, stream>>>(Abf, MP, Vt, MP, AVb, DM, MP, 1.f, MP);

  // Y = AV @ Wo -> f32 d_out (rows < 500)
  transpose_w<<<g_tr, blk, 0, stream>>>(Wo, Wt);
  gemm_nt<float><<<g_qkv, blk, 0, stream>>>(AVb, DM, Wt, DM, Yout, DM, DM, 1.f, N_TOK);
}

// Round 5
// 243.714 us; speedup vs baseline: 8.9106x; 1.2033x over previous
//
#include <hip/hip_runtime.h>
#include <hip/hip_bf16.h>

// RelationAwareSelfAttention  N=500, DM=DK=DV=2048, KWIN=10
// Round 5: fused QKV GEMM, 128x128 MFMA tile w/ register prefetch,
// single prep kernel for weight transposes. ws ~46 MB (ws_size ~268 MB).

#define N_TOK 500
#define MP 512
#define DM 2048
#define NQKV 6144
#define KWIN_ 10
#define NREL 21

typedef __hip_bfloat16 bf16;
typedef __attribute__((ext_vector_type(8))) short short8;
typedef __attribute__((ext_vector_type(4))) float floatx4;

__device__ inline void store_c(float* p, float v) { *p = v; }
__device__ inline void store_c(bf16* p, float v) { *p = __float2bfloat16(v); }

// All 4 weights: W[2048,2048] f32 -> WT[n][k] bf16. z selects weight.
__global__ __launch_bounds__(256) void prep_weights(
    const float* __restrict__ Wq, const float* __restrict__ Wk,
    const float* __restrict__ Wv, const float* __restrict__ Wo,
    bf16* __restrict__ WqkvT, bf16* __restrict__ WoT) {
  __shared__ float t[64][65];
  int z = blockIdx.z;
  const float* W = (z == 0) ? Wq : (z == 1) ? Wk : (z == 2) ? Wv : Wo;
  bf16* Out = (z < 3) ? (WqkvT + (long)z * DM * DM) : WoT;
  int k0 = blockIdx.y * 64, n0 = blockIdx.x * 64;
  int c = threadIdx.x & 63, r4 = threadIdx.x >> 6;
#pragma unroll
  for (int i = 0; i < 16; ++i) {
    int r = r4 * 16 + i;
    t[r][c] = W[(long)(k0 + r) * DM + n0 + c];
  }
  __syncthreads();
#pragma unroll
  for (int i = 0; i < 16; ++i) {
    int r = r4 * 16 + i;
    Out[(long)(n0 + r) * DM + k0 + c] = __float2bfloat16(t[c][r]);
  }
}

// X rows (pad to 512 with zeros) + wk rows -> bf16. Blocks 0..511: X, 512..532: wk.
__global__ __launch_bounds__(256) void cvt_all(const float* __restrict__ X,
                                               const float* __restrict__ wk,
                                               bf16* __restrict__ Xb,
                                               bf16* __restrict__ wkb) {
  int b = blockIdx.x;
  int c0 = threadIdx.x * 8;
  bf16 v[8];
  if (b < MP) {
    if (b < N_TOK) {
      const float* p = X + (long)b * DM + c0;
#pragma unroll
      for (int j = 0; j < 8; ++j) v[j] = __float2bfloat16(p[j]);
    } else {
#pragma unroll
      for (int j = 0; j < 8; ++j) v[j] = __float2bfloat16(0.f);
    }
    *(short8*)(Xb + (long)b * DM + c0) = *(short8*)v;
  } else {
    int r = b - MP;
    const float* p = wk + (long)r * DM + c0;
#pragma unroll
    for (int j = 0; j < 8; ++j) v[j] = __float2bfloat16(p[j]);
    *(short8*)(wkb + (long)r * DM + c0) = *(short8*)v;
  }
}

// NT MFMA GEMM: C[M,N] = alpha * A[M,K] @ B[N,K]^T, 128x128 tile, BK=32,
// 512 threads (8 waves; wave tile 32x64 = 2x4 mfma_16x16x32 accs),
// register prefetch of next K-slice. Grid (N/128, M/128). Rows >= m_store skipped.
template <typename CT>
__global__ __launch_bounds__(512) void gemm_nt128(
    const bf16* __restrict__ A, int lda, const bf16* __restrict__ B, int ldb,
    CT* __restrict__ C, int ldc, int K, float alpha, int m_store) {
  __shared__ __align__(16) bf16 As[128][40];  // 80 B rows: 16B-aligned
  __shared__ __align__(16) bf16 Bs[128][40];
  int tid = threadIdx.x;
  long row0 = blockIdx.y * 128, col0 = blockIdx.x * 128;
  int lane = tid & 63, w = tid >> 6;
  int wr = (w & 3) * 32, wc = (w >> 2) * 64;
  int l16 = lane & 15, l4 = lane >> 4;
  int sr = tid >> 2, sk = (tid & 3) * 8;  // staging: row 0..127, k-chunk
  const bf16* ap = A + (row0 + sr) * (long)lda + sk;
  const bf16* bp = B + (col0 + sr) * (long)ldb + sk;
  floatx4 acc[2][4] = {};
  short8 ra = *(const short8*)ap;
  short8 rb = *(const short8*)bp;
  for (int k0 = 0; k0 < K; k0 += 32) {
    *(short8*)&As[sr][sk] = ra;
    *(short8*)&Bs[sr][sk] = rb;
    __syncthreads();
    if (k0 + 32 < K) {  // prefetch next slice; latency overlaps compute
      ra = *(const short8*)(ap + k0 + 32);
      rb = *(const short8*)(bp + k0 + 32);
    }
    short8 af0 = *(short8*)&As[wr + l16][l4 * 8];
    short8 af1 = *(short8*)&As[wr + 16 + l16][l4 * 8];
    short8 bg0 = *(short8*)&Bs[wc + l16][l4 * 8];
    short8 bg1 = *(short8*)&Bs[wc + 16 + l16][l4 * 8];
    short8 bg2 = *(short8*)&Bs[wc + 32 + l16][l4 * 8];
    short8 bg3 = *(short8*)&Bs[wc + 48 + l16][l4 * 8];
    acc[0][0] = __builtin_amdgcn_mfma_f32_16x16x32_bf16(af0, bg0, acc[0][0], 0, 0, 0);
    acc[0][1] = __builtin_amdgcn_mfma_f32_16x16x32_bf16(af0, bg1, acc[0][1], 0, 0, 0);
    acc[0][2] = __builtin_amdgcn_mfma_f32_16x16x32_bf16(af0, bg2, acc[0][2], 0, 0, 0);
    acc[0][3] = __builtin_amdgcn_mfma_f32_16x16x32_bf16(af0, bg3, acc[0][3], 0, 0, 0);
    acc[1][0] = __builtin_amdgcn_mfma_f32_16x16x32_bf16(af1, bg0, acc[1][0], 0, 0, 0);
    acc[1][1] = __builtin_amdgcn_mfma_f32_16x16x32_bf16(af1, bg1, acc[1][1], 0, 0, 0);
    acc[1][2] = __builtin_amdgcn_mfma_f32_16x16x32_bf16(af1, bg2, acc[1][2], 0, 0, 0);
    acc[1][3] = __builtin_amdgcn_mfma_f32_16x16x32_bf16(af1, bg3, acc[1][3], 0, 0, 0);
    __syncthreads();
  }
  // C layout: col = lane&15, row = (lane>>4)*4 + i  [m89-verified]
#pragma unroll
  for (int mi = 0; mi < 2; ++mi)
#pragma unroll
    for (int ni = 0; ni < 4; ++ni)
#pragma unroll
      for (int i = 0; i < 4; ++i) {
        long r = row0 + wr + mi * 16 + l4 * 4 + i;
        if (r >= m_store) continue;
        long c = col0 + wc + ni * 16 + l16;
        store_c(&C[r * ldc + c], alpha * acc[mi][ni][i]);
      }
}

// V[512,2048] (ld ldv) -> Vt[2048,512] bf16
__global__ __launch_bounds__(256) void transpose_v(const bf16* __restrict__ V,
                                                   int ldv,
                                                   bf16* __restrict__ Vt) {
  __shared__ bf16 t[64][65];
  int r0 = blockIdx.y * 64, c0 = blockIdx.x * 64;
  int c = threadIdx.x & 63, r4 = threadIdx.x >> 6;
#pragma unroll
  for (int i = 0; i < 16; ++i) {
    int r = r4 * 16 + i;
    t[r][c] = V[(long)(r0 + r) * ldv + c0 + c];
  }
  __syncthreads();
#pragma unroll
  for (int i = 0; i < 16; ++i) {
    int r = r4 * 16 + i;
    Vt[(long)(c0 + r) * MP + r0 + c] = t[c][r];
  }
}

// QR[i,r] = scale * sum_d Q[i,d] * wkb[r,d]; Q ld = ldq. QR ld = 32.
__global__ __launch_bounds__(256) void qr_kernel(const bf16* __restrict__ Q,
                                                 int ldq,
                                                 const bf16* __restrict__ wkb,
                                                 float* __restrict__ QR,
                                                 float scale) {
  int i = blockIdx.x;
  int lane = threadIdx.x & 63, wid = threadIdx.x >> 6;
  for (int r = wid; r < NREL; r += 4) {
    float p = 0.f;
    for (int d = lane * 8; d < DM; d += 64 * 8) {
      short8 q8 = *(const short8*)(Q + (long)i * ldq + d);
      short8 w8 = *(const short8*)(wkb + (long)r * DM + d);
#pragma unroll
      for (int j = 0; j < 8; ++j)
        p += __bfloat162float(((const bf16*)&q8)[j]) *
             __bfloat162float(((const bf16*)&w8)[j]);
    }
#pragma unroll
    for (int o = 32; o > 0; o >>= 1) p += __shfl_down(p, o);
    if (lane == 0) QR[i * 32 + r] = p * scale;
  }
}

// bias + mask + softmax. S ld=512 f32. Aout f32 (d_out), Abf bf16 [512][512] padded.
__global__ __launch_bounds__(256) void softmax_kernel(
    const float* __restrict__ S, const float* __restrict__ QR,
    const int* __restrict__ mask, float* __restrict__ Aout,
    bf16* __restrict__ Abf) {
  int i = blockIdx.x;
  int tid = threadIdx.x;
  if (i >= N_TOK) {
    Abf[(long)i * MP + tid] = __float2bfloat16(0.f);
    Abf[(long)i * MP + tid + 256] = __float2bfloat16(0.f);
    return;
  }
  int lane = tid & 63, wid = tid >> 6;
  __shared__ float red[4];
  float v0, v1 = -1e30f;
  int j0 = tid, j1 = tid + 256;
  {
    int rel = j0 - i;
    rel = rel < -KWIN_ ? -KWIN_ : (rel > KWIN_ ? KWIN_ : rel);
    float s = S[(long)i * MP + j0] + QR[i * 32 + rel + KWIN_];
    if (mask[(long)i * N_TOK + j0] == 0) s = -1e9f;
    v0 = s;
  }
  if (j1 < N_TOK) {
    int rel = j1 - i;
    rel = rel < -KWIN_ ? -KWIN_ : (rel > KWIN_ ? KWIN_ : rel);
    float s = S[(long)i * MP + j1] + QR[i * 32 + rel + KWIN_];
    if (mask[(long)i * N_TOK + j1] == 0) s = -1e9f;
    v1 = s;
  }
  float mx = fmaxf(v0, v1);
#pragma unroll
  for (int o = 32; o > 0; o >>= 1) mx = fmaxf(mx, __shfl_down(mx, o));
  if (lane == 0) red[wid] = mx;
  __syncthreads();
  if (tid == 0) red[0] = fmaxf(fmaxf(red[0], red[1]), fmaxf(red[2], red[3]));
  __syncthreads();
  mx = red[0];
  __syncthreads();
  float e0 = expf(v0 - mx);
  float e1 = (j1 < N_TOK) ? expf(v1 - mx) : 0.f;
  float sum = e0 + e1;
#pragma unroll
  for (int o = 32; o > 0; o >>= 1) sum += __shfl_down(sum, o);
  if (lane == 0) red[wid] = sum;
  __syncthreads();
  if (tid == 0) red[0] = red[0] + red[1] + red[2] + red[3];
  __syncthreads();
  float inv = 1.f / red[0];
  float a0 = e0 * inv, a1 = e1 * inv;
  Aout[(long)i * N_TOK + j0] = a0;
  if (j1 < N_TOK) Aout[(long)i * N_TOK + j1] = a1;
  Abf[(long)i * MP + j0] = __float2bfloat16(a0);
  Abf[(long)i * MP + j1] = __float2bfloat16(a1);  // j1>=500 -> 0
}

extern "C" void kernel_launch(void* const* d_in, const int* in_sizes, int n_in,
                              void* d_out, int out_size, void* d_ws,
                              size_t ws_size, hipStream_t stream) {
  const float* X = (const float*)d_in[0];
  const int* mask = (const int*)d_in[1];
  const float* Wq = (const float*)d_in[2];
  const float* Wk = (const float*)d_in[3];
  const float* Wv = (const float*)d_in[4];
  const float* Wo = (const float*)d_in[5];
  const float* wk = (const float*)d_in[6];

  float* Yout = (float*)d_out;            // [500,2048]
  float* Aout = Yout + (long)N_TOK * DM;  // [500,500]

  const long MB = 1 << 20;
  char* p = (char*)d_ws;
  bf16* Xb = (bf16*)p;                    // [512][2048]    2 MB
  bf16* WqkvT = (bf16*)(p + 2 * MB);      // [6144][2048]  24 MB
  bf16* WoT = (bf16*)(p + 26 * MB);       // [2048][2048]   8 MB
  bf16* QKV = (bf16*)(p + 34 * MB);       // [512][6144]    6 MB (unscaled)
  bf16* Vt = (bf16*)(p + 40 * MB);        // [2048][512]    2 MB
  float* S = (float*)(p + 42 * MB);       // [512][512]     1 MB
  bf16* Abf = (bf16*)(p + 43 * MB);       // [512][512]   0.5 MB
  bf16* AVb = (bf16*)(p + 44 * MB);       // [512][2048]    2 MB
  bf16* wkb = (bf16*)(p + 46 * MB);       // [21][2048]
  float* QR = (float*)(p + 47 * MB);      // [512][32]

  const float scale = 0.022097086912079608f;  // 1/sqrt(2048)
  dim3 b256(256), b512(512);

  prep_weights<<<dim3(32, 32, 4), b256, 0, stream>>>(Wq, Wk, Wv, Wo, WqkvT, WoT);
  cvt_all<<<dim3(MP + NREL), b256, 0, stream>>>(X, wk, Xb, wkb);

  // QKV[512,6144] = X @ [Wq|Wk|Wv]  (unscaled)
  gemm_nt128<bf16><<<dim3(48, 4), b512, 0, stream>>>(
      Xb, DM, WqkvT, DM, QKV, NQKV, DM, 1.f, MP);

  // Vt = V^T  (V = QKV cols 4096..6143)
  transpose_v<<<dim3(32, 8), b256, 0, stream>>>(QKV + 4096, NQKV, Vt);

  // QR = scale * Q @ wk^T
  qr_kernel<<<dim3(N_TOK), b256, 0, stream>>>(QKV, NQKV, wkb, QR, scale);

  // S = scale * Q @ K^T  [512,512] f32
  gemm_nt128<float><<<dim3(4, 4), b512, 0, stream>>>(
      QKV, NQKV, QKV + 2048, NQKV, S, MP, DM, scale, MP);

  // softmax -> Aout (d_out) + Abf
  softmax_kernel<<<dim3(MP), b256, 0, stream>>>(S, QR, mask, Aout, Abf);

  // AV = A @ V = NT(Abf, Vt)  [512,2048] bf16, K=512
  gemm_nt128<bf16><<<dim3(16, 4), b512, 0, stream>>>(
      Abf, MP, Vt, MP, AVb, DM, MP, 1.f, MP);

  // Y = AV @ Wo -> f32 (rows < 500)
  gemm_nt128<float><<<dim3(16, 4), b512, 0, stream>>>(
      AVb, DM, WoT, DM, Yout, DM, DM, 1.f, N_TOK);
}

// Round 6
// 193.812 us; speedup vs baseline: 11.2049x; 1.2575x over previous
//
#include <hip/hip_runtime.h>
#include <hip/hip_bf16.h>

// RelationAwareSelfAttention  N=500, DM=DK=DV=2048, KWIN=10
// Round 6: 4-wave 128x128 gemm (wave 64x64, 16 MFMA / 8 LDS reads), split-K,
// merged QK+Vt launch, fused QR+softmax, vectorized prep. 8 launches.

#define N_TOK 500
#define MP 512
#define DM 2048
#define KWIN_ 10
#define NREL 21

typedef __hip_bfloat16 bf16;
typedef __attribute__((ext_vector_type(8))) short short8;
typedef __attribute__((ext_vector_type(4))) float floatx4;

#define NQK 2097152L  // 512*4096
#define NVT 1048576L  // 2048*512
#define NS 262144L    // 512*512
#define NY 1048576L   // 512*2048

__device__ inline float bfj(const short8& v, int j) {
  return __bfloat162float(((const bf16*)&v)[j]);
}

// ---------------- prep: weights transpose+cvt, X/wk cvt ----------------
__global__ __launch_bounds__(256) void prep(
    const float* __restrict__ Wq, const float* __restrict__ Wk,
    const float* __restrict__ Wv, const float* __restrict__ Wo,
    const float* __restrict__ X, const float* __restrict__ wk,
    bf16* __restrict__ WqkT, bf16* __restrict__ WvT, bf16* __restrict__ WoT,
    bf16* __restrict__ Xb, bf16* __restrict__ wkb) {
  int z = blockIdx.z;
  int tid = threadIdx.x;
  if (z == 4) {  // row conversions
    int row = blockIdx.y * 32 + blockIdx.x;
    int c0 = tid * 8;
    bf16 v[8];
    if (row < MP) {
      if (row < N_TOK) {
        const float* p = X + (long)row * DM + c0;
#pragma unroll
        for (int j = 0; j < 8; ++j) v[j] = __float2bfloat16(p[j]);
      } else {
#pragma unroll
        for (int j = 0; j < 8; ++j) v[j] = __float2bfloat16(0.f);
      }
      *(short8*)(Xb + (long)row * DM + c0) = *(short8*)v;
    } else if (row < MP + NREL) {
      int r = row - MP;
      const float* p = wk + (long)r * DM + c0;
#pragma unroll
      for (int j = 0; j < 8; ++j) v[j] = __float2bfloat16(p[j]);
      *(short8*)(wkb + (long)r * DM + c0) = *(short8*)v;
    }
    return;
  }
  const float* W = (z == 0) ? Wq : (z == 1) ? Wk : (z == 2) ? Wv : Wo;
  bf16* Out = (z == 0) ? WqkT
            : (z == 1) ? (WqkT + (long)DM * DM)
            : (z == 2) ? WvT : WoT;
  __shared__ float t[64][68];  // XOR-swizzled granules, conflict-free both sides
  int k0 = blockIdx.y * 64, n0 = blockIdx.x * 64;
  int rr = tid >> 4, cc = (tid & 15) * 4;
  int gsw = cc >> 2;
#pragma unroll
  for (int p = 0; p < 4; ++p) {
    int r = rr + 16 * p;
    float4 v = *(const float4*)(W + (long)(k0 + r) * DM + n0 + cc);
    *(float4*)&t[r][(gsw ^ (r & 3)) * 4] = v;
  }
  __syncthreads();
#pragma unroll
  for (int s0 = 0; s0 < 2; ++s0) {
    int s = tid + s0 * 256;
    int n = s >> 3, c = s & 7;  // 8 lanes per out row -> 128B contiguous
    bf16 v[8];
#pragma unroll
    for (int j = 0; j < 8; ++j) {
      int rowt = c * 8 + j;
      int col = ((n >> 2) ^ (rowt & 3)) * 4 + (n & 3);
      v[j] = __float2bfloat16(t[rowt][col]);
    }
    *(short8*)(Out + (long)(n0 + n) * DM + k0 + c * 8) = *(short8*)v;
  }
}

// ---------------- gemm core: 128x128 tile, 4 waves of 64x64 ----------------
// NT: C[M,N] = A[M,K] @ B[N,K]^T over K-slice [kStart, kStart+kLen).
// OUT: 0 -> f32 store, 1 -> bf16 store. No guards (all dims padded).
template <int OUT>
__device__ __forceinline__ void gemm_core(
    const bf16* __restrict__ A, int lda, const bf16* __restrict__ B, int ldb,
    float* __restrict__ Cf, bf16* __restrict__ Cb, int ldc, int kStart,
    int kLen, int row0, int col0) {
  __shared__ __align__(16) bf16 As[128][32];
  __shared__ __align__(16) bf16 Bs[128][32];
  int tid = threadIdx.x;
  int lane = tid & 63, w = tid >> 6;
  int wr = (w & 1) * 64, wc = (w >> 1) * 64;
  int l16 = lane & 15, l4 = lane >> 4;
  int r1 = tid >> 2, c1 = (tid & 3) * 8;  // slot mapping: even bank spread
  const bf16* Ab = A + (long)row0 * lda + kStart;
  const bf16* Bb = B + (long)col0 * ldb + kStart;
  const bf16* a1p = Ab + (long)r1 * lda + c1;
  const bf16* a2p = Ab + (long)(r1 + 64) * lda + c1;
  const bf16* b1p = Bb + (long)r1 * ldb + c1;
  const bf16* b2p = Bb + (long)(r1 + 64) * ldb + c1;
  floatx4 acc[4][4] = {};
  short8 pa0 = *(const short8*)a1p, pa1 = *(const short8*)a2p;
  short8 pb0 = *(const short8*)b1p, pb1 = *(const short8*)b2p;
  for (int k0 = 0; k0 < kLen; k0 += 32) {
    if (k0) __syncthreads();
    *(short8*)&As[r1][c1] = pa0;
    *(short8*)&As[r1 + 64][c1] = pa1;
    *(short8*)&Bs[r1][c1] = pb0;
    *(short8*)&Bs[r1 + 64][c1] = pb1;
    __syncthreads();
    int kn = k0 + 32;
    if (kn < kLen) {  // prefetch next slice (latency overlaps LDS+MFMA)
      pa0 = *(const short8*)(a1p + kn);
      pa1 = *(const short8*)(a2p + kn);
      pb0 = *(const short8*)(b1p + kn);
      pb1 = *(const short8*)(b2p + kn);
    }
    short8 af[4], bg[4];
#pragma unroll
    for (int g = 0; g < 4; ++g)
      af[g] = *(short8*)&As[wr + g * 16 + l16][l4 * 8];
#pragma unroll
    for (int g = 0; g < 4; ++g)
      bg[g] = *(short8*)&Bs[wc + g * 16 + l16][l4 * 8];
#pragma unroll
    for (int g = 0; g < 4; ++g)
#pragma unroll
      for (int h = 0; h < 4; ++h)
        acc[g][h] =
            __builtin_amdgcn_mfma_f32_16x16x32_bf16(af[g], bg[h], acc[g][h], 0, 0, 0);
  }
  // C/D layout: col = lane&15, row = (lane>>4)*4 + i  [m89-verified]
#pragma unroll
  for (int g = 0; g < 4; ++g)
#pragma unroll
    for (int h = 0; h < 4; ++h)
#pragma unroll
      for (int i = 0; i < 4; ++i) {
        long r = row0 + wr + g * 16 + l4 * 4 + i;
        long c = col0 + wc + h * 16 + l16;
        if (OUT == 0)
          Cf[r * ldc + c] = acc[g][h][i];
        else
          Cb[r * ldc + c] = __float2bfloat16(acc[g][h][i]);
      }
}

// Merged QK (splitK2, 256 blocks) + Vt (splitK2, 128 blocks) = 384 blocks.
__global__ __launch_bounds__(256, 2) void gemm_qkvt(
    const bf16* __restrict__ Xb, const bf16* __restrict__ WqkT,
    const bf16* __restrict__ WvT, float* __restrict__ QKp,
    float* __restrict__ Vtp) {
  int id = blockIdx.x;
  if (id < 256) {  // QK: C[512,4096] = Xb @ WqkT^T
    int z = id >> 7, t = id & 127;
    int col0 = (t & 31) * 128, row0 = (t >> 5) * 128;
    gemm_core<0>(Xb, DM, WqkT, DM, QKp + (long)z * NQK, nullptr, 4096,
                 z * 1024, 1024, row0, col0);
  } else {  // Vt: C[2048,512] = WvT @ Xb^T
    int id2 = id - 256;
    int z = id2 >> 6, t = id2 & 63;
    int col0 = (t & 3) * 128, row0 = (t >> 2) * 128;
    gemm_core<0>(WvT, DM, Xb, DM, Vtp + (long)z * NVT, nullptr, MP, z * 1024,
                 1024, row0, col0);
  }
}

// Generic split-K gemm. grid (N/128, M/128, splits).
template <int OUT>
__global__ __launch_bounds__(256, 2) void gemm_k(
    const bf16* __restrict__ A, int lda, const bf16* __restrict__ B, int ldb,
    float* __restrict__ Cf, bf16* __restrict__ Cb, int ldc, int sliceK,
    long cstride) {
  float* cf = (OUT == 0) ? Cf + (long)blockIdx.z * cstride : nullptr;
  gemm_core<OUT>(A, lda, B, ldb, cf, Cb, ldc, blockIdx.z * sliceK, sliceK,
                 blockIdx.y * 128, blockIdx.x * 128);
}

// Sum 2 f32 partials -> bf16, for QKp->QKbf and Vtp->Vtb. grid 1536x256.
__global__ __launch_bounds__(256) void reduce_qkvt(
    const float* __restrict__ QKp, const float* __restrict__ Vtp,
    bf16* __restrict__ QKbf, bf16* __restrict__ Vtb) {
  long e = ((long)blockIdx.x * 256 + threadIdx.x) * 8;
  const float* p0;
  long stride;
  bf16* out;
  long eo;
  if (e < NQK) {
    p0 = QKp + e; stride = NQK; out = QKbf; eo = e;
  } else {
    eo = e - NQK; p0 = Vtp + eo; stride = NVT; out = Vtb;
  }
  float4 a0 = *(const float4*)p0, a1 = *(const float4*)(p0 + 4);
  float4 b0 = *(const float4*)(p0 + stride), b1 = *(const float4*)(p0 + stride + 4);
  bf16 v[8];
  v[0] = __float2bfloat16(a0.x + b0.x); v[1] = __float2bfloat16(a0.y + b0.y);
  v[2] = __float2bfloat16(a0.z + b0.z); v[3] = __float2bfloat16(a0.w + b0.w);
  v[4] = __float2bfloat16(a1.x + b1.x); v[5] = __float2bfloat16(a1.y + b1.y);
  v[6] = __float2bfloat16(a1.z + b1.z); v[7] = __float2bfloat16(a1.w + b1.w);
  *(short8*)(out + eo) = *(short8*)v;
}

// Yout[<500] = Yp[0] + Yp[1]. grid 500x256.
__global__ __launch_bounds__(256) void reduce_y(const float* __restrict__ Yp,
                                                float* __restrict__ Yout) {
  long e = (long)blockIdx.x * 2048 + threadIdx.x * 8;
  float4 a0 = *(const float4*)(Yp + e), a1 = *(const float4*)(Yp + e + 4);
  float4 b0 = *(const float4*)(Yp + NY + e), b1 = *(const float4*)(Yp + NY + e + 4);
  float4 o0 = {a0.x + b0.x, a0.y + b0.y, a0.z + b0.z, a0.w + b0.w};
  float4 o1 = {a1.x + b1.x, a1.y + b1.y, a1.z + b1.z, a1.w + b1.w};
  *(float4*)(Yout + e) = o0;
  *(float4*)(Yout + e + 4) = o1;
}

// QR (21 dots of K=2048) + sum 4 S-partials + scale + bias + mask + softmax.
__global__ __launch_bounds__(256) void softmax_qr(
    const float* __restrict__ Sp, const bf16* __restrict__ QKbf,
    const bf16* __restrict__ wkb, const int* __restrict__ mask,
    float* __restrict__ Aout, bf16* __restrict__ Abf) {
  int i = blockIdx.x;
  int tid = threadIdx.x;
  if (i >= N_TOK) {  // pad rows of Abf -> 0
    Abf[(long)i * MP + tid] = __float2bfloat16(0.f);
    Abf[(long)i * MP + tid + 256] = __float2bfloat16(0.f);
    return;
  }
  int lane = tid & 63, w = tid >> 6;
  __shared__ float sQR[24];
  __shared__ float red[4];
  // ---- QR: wave w handles r = w, w+4, ... (Q row preloaded once) ----
  short8 q[4];
#pragma unroll
  for (int s = 0; s < 4; ++s)
    q[s] = *(const short8*)(QKbf + (long)i * 4096 + s * 512 + lane * 8);
  for (int r = w; r < NREL; r += 4) {
    float p = 0.f;
#pragma unroll
    for (int s = 0; s < 4; ++s) {
      short8 wv = *(const short8*)(wkb + (long)r * DM + s * 512 + lane * 8);
#pragma unroll
      for (int j = 0; j < 8; ++j) p += bfj(q[s], j) * bfj(wv, j);
    }
#pragma unroll
    for (int o = 32; o > 0; o >>= 1) p += __shfl_down(p, o);
    if (lane == 0) sQR[r] = p;
  }
  __syncthreads();
  // ---- softmax over j (each thread owns j0=tid, j1=tid+256) ----
  const float scale = 0.022097086912079608f;  // 1/sqrt(2048)
  float v0, v1 = -1e30f;
  int j0 = tid, j1 = tid + 256;
  {
    float s = Sp[(long)i * MP + j0] + Sp[NS + (long)i * MP + j0] +
              Sp[2 * NS + (long)i * MP + j0] + Sp[3 * NS + (long)i * MP + j0];
    int rel = j0 - i;
    rel = rel < -KWIN_ ? -KWIN_ : (rel > KWIN_ ? KWIN_ : rel);
    s = scale * (s + sQR[rel + KWIN_]);
    if (mask[(long)i * N_TOK + j0] == 0) s = -1e9f;
    v0 = s;
  }
  if (j1 < N_TOK) {
    float s = Sp[(long)i * MP + j1] + Sp[NS + (long)i * MP + j1] +
              Sp[2 * NS + (long)i * MP + j1] + Sp[3 * NS + (long)i * MP + j1];
    int rel = j1 - i;
    rel = rel < -KWIN_ ? -KWIN_ : (rel > KWIN_ ? KWIN_ : rel);
    s = scale * (s + sQR[rel + KWIN_]);
    if (mask[(long)i * N_TOK + j1] == 0) s = -1e9f;
    v1 = s;
  }
  float mx = fmaxf(v0, v1);
#pragma unroll
  for (int o = 32; o > 0; o >>= 1) mx = fmaxf(mx, __shfl_down(mx, o));
  if (lane == 0) red[w] = mx;
  __syncthreads();
  if (tid == 0) red[0] = fmaxf(fmaxf(red[0], red[1]), fmaxf(red[2], red[3]));
  __syncthreads();
  mx = red[0];
  __syncthreads();
  float e0 = expf(v0 - mx);
  float e1 = (j1 < N_TOK) ? expf(v1 - mx) : 0.f;
  float sum = e0 + e1;
#pragma unroll
  for (int o = 32; o > 0; o >>= 1) sum += __shfl_down(sum, o);
  if (lane == 0) red[w] = sum;
  __syncthreads();
  if (tid == 0) red[0] = red[0] + red[1] + red[2] + red[3];
  __syncthreads();
  float inv = 1.f / red[0];
  float a0 = e0 * inv, a1 = e1 * inv;
  Aout[(long)i * N_TOK + j0] = a0;
  if (j1 < N_TOK) Aout[(long)i * N_TOK + j1] = a1;
  Abf[(long)i * MP + j0] = __float2bfloat16(a0);
  Abf[(long)i * MP + j1] = __float2bfloat16(a1);  // j1>=500 -> 0
}

extern "C" void kernel_launch(void* const* d_in, const int* in_sizes, int n_in,
                              void* d_out, int out_size, void* d_ws,
                              size_t ws_size, hipStream_t stream) {
  const float* X = (const float*)d_in[0];
  const int* mask = (const int*)d_in[1];
  const float* Wq = (const float*)d_in[2];
  const float* Wk = (const float*)d_in[3];
  const float* Wv = (const float*)d_in[4];
  const float* Wo = (const float*)d_in[5];
  const float* wk = (const float*)d_in[6];

  float* Yout = (float*)d_out;            // [500,2048]
  float* Aout = Yout + (long)N_TOK * DM;  // [500,500]

  const long MB = 1 << 20;
  char* p = (char*)d_ws;
  bf16* Xb = (bf16*)p;                    // [512][2048]        2 MB
  bf16* WqkT = (bf16*)(p + 2 * MB);       // [4096][2048]      16 MB
  bf16* WvT = (bf16*)(p + 18 * MB);       // [2048][2048]       8 MB
  bf16* WoT = (bf16*)(p + 26 * MB);       // [2048][2048]       8 MB
  bf16* wkb = (bf16*)(p + 34 * MB);       // [21][2048]
  float* QKp = (float*)(p + 35 * MB);     // [2][512][4096]    16 MB
  float* Vtp = (float*)(p + 51 * MB);     // [2][2048][512]     8 MB
  bf16* QKbf = (bf16*)(p + 59 * MB);      // [512][4096]        4 MB
  bf16* Vtb = (bf16*)(p + 63 * MB);       // [2048][512]        2 MB
  float* Sp = (float*)(p + 65 * MB);      // [4][512][512]      4 MB
  bf16* Abf = (bf16*)(p + 69 * MB);       // [512][512]       0.5 MB
  bf16* AVbf = (bf16*)(p + 70 * MB);      // [512][2048]        2 MB
  float* Yp = (float*)(p + 72 * MB);      // [2][512][2048]     8 MB

  dim3 b256(256);

  // 1. prep: weights -> transposed bf16; X/wk -> bf16
  prep<<<dim3(32, 32, 5), b256, 0, stream>>>(Wq, Wk, Wv, Wo, X, wk, WqkT, WvT,
                                             WoT, Xb, wkb);
  // 2. QK (splitK2) + Vt (splitK2), 384 blocks
  gemm_qkvt<<<dim3(384), b256, 0, stream>>>(Xb, WqkT, WvT, QKp, Vtp);
  // 3. partials -> bf16
  reduce_qkvt<<<dim3(1536), b256, 0, stream>>>(QKp, Vtp, QKbf, Vtb);
  // 4. S partials: Q @ K^T, splitK4 (unscaled)
  gemm_k<0><<<dim3(4, 4, 4), b256, 0, stream>>>(QKbf, 4096, QKbf + 2048, 4096,
                                                Sp, nullptr, MP, 512, NS);
  // 5. QR + softmax -> Aout (d_out) + Abf
  softmax_qr<<<dim3(MP), b256, 0, stream>>>(Sp, QKbf, wkb, mask, Aout, Abf);
  // 6. AV = Abf @ Vtb^T -> bf16
  gemm_k<1><<<dim3(16, 4, 1), b256, 0, stream>>>(Abf, MP, Vtb, MP, nullptr,
                                                 AVbf, DM, MP, 0);
  // 7. Y partials: AVbf @ WoT^T, splitK2
  gemm_k<0><<<dim3(16, 4, 2), b256, 0, stream>>>(AVbf, DM, WoT, DM, Yp,
                                                 nullptr, DM, 1024, NY);
  // 8. Y = sum partials -> f32 d_out (rows < 500)
  reduce_y<<<dim3(N_TOK), b256, 0, stream>>>(Yp, Yout);
}